// Round 3
// baseline (297.749 us; speedup 1.0000x reference)
//
#include <hip/hip_runtime.h>

// SymmetricContraction: out[b,c] = sum_w x_w U1[w] w1[b,c]
//                               + sum_{w,v}   x_w x_v   (U2 . w2[b,:,c])_{wv}
//                               + sum_{w,v,i} x_w x_v x_i (U3 . w3[b,:,c])_{wvi}
// U3 pre-symmetrized onto 816 multisets {a<=b<=c}: 94208 -> 18768 MACs/(b,c).
//
// Round-3 structure: R=4 thread coarsening. Broadcast ds_read_b128 costs ~6cyc
// of the per-CU LDS pipe regardless of how many lanes use it, so per multiset:
// LDS = 6 reads x 6cyc (per wave, CU-shared), VALU = ~50R cyc (per wave,
// SIMD-local). LDS:VALU balance needs R>=3.5 INDEPENDENT of occupancy.
// R=4: 256-thr block, 4 b's/block, grid=256 (b_max=1023 -- the round-2 crash
// was grid=512 reading b up to 2047). cc-loop paired so the per-row x reads
// merge into ds_read2_b32. Core floor: 65us VALU / 56us LDS -> VALU-bound.

#define B_   1024
#define C_   256
#define L_   16
#define E_   10
#define K3_  23
#define K2_  4

#define NM3  816   // #multisets a<=b<=c of 16
#define NM2  136   // #pairs a<=b
#define K3P  24    // k padded to 24 floats per row (96B)

__device__ __host__ __forceinline__ int tri_(int n) { return n * (n + 1) / 2; }
__device__ __host__ __forceinline__ int tet_(int n) { return n * (n + 1) * (n + 2) / 6; }

// ---------------- prep: symmetrize U3 / U2 into workspace ----------------
__global__ void prep_kernel(const float* __restrict__ U3,
                            const float* __restrict__ U2,
                            float* __restrict__ wsU3,
                            float* __restrict__ wsU2) {
  int tid = blockIdx.x * blockDim.x + threadIdx.x;
  if (tid < L_ * L_ * L_) {
    const int a = tid >> 8, b = (tid >> 4) & 15, c = tid & 15;
    if (a <= b && b <= c) {
      const int m = (tet_(16) - tet_(16 - a)) + (tri_(16 - a) - tri_(16 - b)) + (c - b);
      int pw[6] = {a, a, b, b, c, c};
      int pv[6] = {b, c, a, c, a, b};
      int pi[6] = {c, b, c, a, b, a};
      bool use[6];
      for (int p = 0; p < 6; p++) {
        bool dup = false;
        for (int q = 0; q < p; q++)
          dup = dup || (pw[p] == pw[q] && pv[p] == pv[q] && pi[p] == pi[q]);
        use[p] = !dup;
      }
      for (int k = 0; k < K3_; k++) {
        float s = 0.f;
        for (int p = 0; p < 6; p++)
          if (use[p]) s += U3[((pw[p] * L_ + pv[p]) * L_ + pi[p]) * K3_ + k];
        wsU3[m * K3P + k] = s;
      }
      wsU3[m * K3P + K3_] = 0.f;  // pad
    }
  } else if (tid < L_ * L_ * L_ + L_ * L_) {
    const int p = tid - L_ * L_ * L_;
    const int a = p >> 4, b = p & 15;
    if (a <= b) {
      const int pidx = (136 - tri_(16 - a)) + (b - a);
      for (int k2 = 0; k2 < K2_; k2++) {
        float s = U2[(a * L_ + b) * K2_ + k2];
        if (a != b) s += U2[(b * L_ + a) * K2_ + k2];
        wsU2[pidx * K2_ + k2] = s;
      }
    }
  }
}

// ---------------- main: one thread per FOUR (b,c) rows ----------------
// block = 256 threads (c = tid), 4 b's per block; grid = 256 blocks (1/CU).
__global__ __launch_bounds__(256) void symcon_kernel(
    const float* __restrict__ x,   // [B,C,L]
    const float* __restrict__ y,   // [B,E]
    const float* __restrict__ U1,  // [L,1]
    const float* __restrict__ W3,  // [E,K3,C]
    const float* __restrict__ W2,  // [E,K2,C]
    const float* __restrict__ W1,  // [E,1,C]
    const float* __restrict__ wsU3,
    const float* __restrict__ wsU2,
    float* __restrict__ out)       // [B,C]
{
  __shared__ __attribute__((aligned(16))) float sU3[NM3 * K3P];  // 78336 B
  __shared__ __attribute__((aligned(16))) float sU2[NM2 * K2_];  //  2176 B
  __shared__ float sU1[L_];
  __shared__ float sY[4 * E_];
  // 4 x-rows per thread: thread base tid*69 (stride 69: odd -> 2-way = free),
  // row j at +j*17 (ds_read2 offsets 17/34/51 dwords, all < 256).
  __shared__ float sX[256 * 69];                                 // 70656 B

  const int tid = threadIdx.x;   // == c
  const int c   = tid;
  const int b0  = blockIdx.x * 4;

  // stage U tables (wsU3 L2-resident; 256 blocks broadcast-read it)
  for (int i = tid; i < NM3 * K3P / 4; i += 256)
    ((float4*)sU3)[i] = ((const float4*)wsU3)[i];
  for (int i = tid; i < NM2 * K2_ / 4; i += 256)
    ((float4*)sU2)[i] = ((const float4*)wsU2)[i];
  if (tid < L_) sU1[tid] = U1[tid];
  if (tid < 4 * E_) sY[tid] = y[(b0 + tid / E_) * E_ + tid % E_];

  // stage this thread's four x rows
  float* xbase = &sX[tid * 69];
  #pragma unroll
  for (int j = 0; j < 4; j++) {
    const float4* xg = (const float4*)(x + ((size_t)(b0 + j) * C_ + c) * L_);
    float* xr = xbase + j * 17;
    #pragma unroll
    for (int i = 0; i < 4; i++) {
      float4 v = xg[i];
      xr[i * 4 + 0] = v.x; xr[i * 4 + 1] = v.y;
      xr[i * 4 + 2] = v.z; xr[i * 4 + 3] = v.w;
    }
  }
  __syncthreads();

  const float* xp0 = xbase;
  const float* xp1 = xbase + 17;
  const float* xp2 = xbase + 34;
  const float* xp3 = xbase + 51;

  // ---- nu=3 core: t[j][k] = sum_m x_a x_b x_c * Us3[m,k] ----
  float t[4][K3P];
  #pragma unroll
  for (int j = 0; j < 4; j++)
    #pragma unroll
    for (int k = 0; k < K3P; k++) t[j][k] = 0.f;

  const float4* u4 = (const float4*)sU3;
  for (int a = 0; a < L_; a++) {
    const float xa0 = xp0[a], xa1 = xp1[a], xa2 = xp2[a], xa3 = xp3[a];
    for (int b = a; b < L_; b++) {
      const float xb0 = xa0 * xp0[b], xb1 = xa1 * xp1[b];
      const float xb2 = xa2 * xp2[b], xb3 = xa3 * xp3[b];
      int cc = b;
      // paired: 2 multisets per iteration (adjacent x reads merge -> ds_read2)
      for (; cc + 1 < L_; cc += 2) {
        float pA[4], pB[4];
        pA[0] = xb0 * xp0[cc]; pB[0] = xb0 * xp0[cc + 1];
        pA[1] = xb1 * xp1[cc]; pB[1] = xb1 * xp1[cc + 1];
        pA[2] = xb2 * xp2[cc]; pB[2] = xb2 * xp2[cc + 1];
        pA[3] = xb3 * xp3[cc]; pB[3] = xb3 * xp3[cc + 1];
        #pragma unroll
        for (int k4 = 0; k4 < K3P / 4; k4++) {
          const float4 uA = u4[k4];             // row m
          const float4 uB = u4[K3P / 4 + k4];   // row m+1
          #pragma unroll
          for (int j = 0; j < 4; j++) {
            t[j][k4 * 4 + 0] += pA[j] * uA.x;
            t[j][k4 * 4 + 1] += pA[j] * uA.y;
            t[j][k4 * 4 + 2] += pA[j] * uA.z;
            t[j][k4 * 4 + 3] += pA[j] * uA.w;
            t[j][k4 * 4 + 0] += pB[j] * uB.x;
            t[j][k4 * 4 + 1] += pB[j] * uB.y;
            t[j][k4 * 4 + 2] += pB[j] * uB.z;
            t[j][k4 * 4 + 3] += pB[j] * uB.w;
          }
        }
        u4 += 2 * (K3P / 4);
      }
      if (cc < L_) {  // odd tail (one multiset)
        float q[4];
        q[0] = xb0 * xp0[cc]; q[1] = xb1 * xp1[cc];
        q[2] = xb2 * xp2[cc]; q[3] = xb3 * xp3[cc];
        #pragma unroll
        for (int k4 = 0; k4 < K3P / 4; k4++) {
          const float4 uA = u4[k4];
          #pragma unroll
          for (int j = 0; j < 4; j++) {
            t[j][k4 * 4 + 0] += q[j] * uA.x;
            t[j][k4 * 4 + 1] += q[j] * uA.y;
            t[j][k4 * 4 + 2] += q[j] * uA.z;
            t[j][k4 * 4 + 3] += q[j] * uA.w;
          }
        }
        u4 += K3P / 4;
      }
    }
  }

  // ---- epilogue (x4 rows) ----
  float yg[4][E_];
  #pragma unroll
  for (int j = 0; j < 4; j++)
    #pragma unroll
    for (int e = 0; e < E_; e++) yg[j][e] = sY[j * E_ + e];

  float res[4] = {0.f, 0.f, 0.f, 0.f};

  // nu=3: contract t with w3[b,:,c]  (W3 reads coalesced over c, L2-resident)
  #pragma unroll
  for (int k = 0; k < K3_; k++) {
    const float* w3p = &W3[k * C_ + c];
    float w3[4] = {0.f, 0.f, 0.f, 0.f};
    #pragma unroll
    for (int e = 0; e < E_; e++) {
      const float w = w3p[e * K3_ * C_];
      #pragma unroll
      for (int j = 0; j < 4; j++) w3[j] += w * yg[j][e];
    }
    #pragma unroll
    for (int j = 0; j < 4; j++) res[j] += t[j][k] * w3[j];
  }

  // nu=2
  float w2r[4][K2_];
  #pragma unroll
  for (int k2 = 0; k2 < K2_; k2++) {
    const float* w2p = &W2[k2 * C_ + c];
    float s[4] = {0.f, 0.f, 0.f, 0.f};
    #pragma unroll
    for (int e = 0; e < E_; e++) {
      const float w = w2p[e * K2_ * C_];
      #pragma unroll
      for (int j = 0; j < 4; j++) s[j] += w * yg[j][e];
    }
    #pragma unroll
    for (int j = 0; j < 4; j++) w2r[j][k2] = s[j];
  }
  {
    float acc[4] = {0.f, 0.f, 0.f, 0.f};
    int p = 0;
    for (int a = 0; a < L_; a++) {
      const float xa0 = xp0[a], xa1 = xp1[a], xa2 = xp2[a], xa3 = xp3[a];
      for (int b2 = a; b2 < L_; b2++) {
        const float4 uv = *((const float4*)&sU2[p * K2_]);
        const float pab0 = xa0 * xp0[b2], pab1 = xa1 * xp1[b2];
        const float pab2 = xa2 * xp2[b2], pab3 = xa3 * xp3[b2];
        acc[0] += pab0 * (uv.x * w2r[0][0] + uv.y * w2r[0][1] + uv.z * w2r[0][2] + uv.w * w2r[0][3]);
        acc[1] += pab1 * (uv.x * w2r[1][0] + uv.y * w2r[1][1] + uv.z * w2r[1][2] + uv.w * w2r[1][3]);
        acc[2] += pab2 * (uv.x * w2r[2][0] + uv.y * w2r[2][1] + uv.z * w2r[2][2] + uv.w * w2r[2][3]);
        acc[3] += pab3 * (uv.x * w2r[3][0] + uv.y * w2r[3][1] + uv.z * w2r[3][2] + uv.w * w2r[3][3]);
        p++;
      }
    }
    #pragma unroll
    for (int j = 0; j < 4; j++) res[j] += acc[j];
  }

  // nu=1
  {
    float w1v[4] = {0.f, 0.f, 0.f, 0.f};
    #pragma unroll
    for (int e = 0; e < E_; e++) {
      const float w = W1[e * C_ + c];
      #pragma unroll
      for (int j = 0; j < 4; j++) w1v[j] += w * yg[j][e];
    }
    float u1x[4] = {0.f, 0.f, 0.f, 0.f};
    #pragma unroll
    for (int w = 0; w < L_; w++) {
      const float uw = sU1[w];
      u1x[0] += uw * xp0[w]; u1x[1] += uw * xp1[w];
      u1x[2] += uw * xp2[w]; u1x[3] += uw * xp3[w];
    }
    #pragma unroll
    for (int j = 0; j < 4; j++) res[j] += w1v[j] * u1x[j];
  }

  #pragma unroll
  for (int j = 0; j < 4; j++)
    out[(size_t)(b0 + j) * C_ + c] = res[j];
}

extern "C" void kernel_launch(void* const* d_in, const int* in_sizes, int n_in,
                              void* d_out, int out_size, void* d_ws, size_t ws_size,
                              hipStream_t stream) {
  const float* x  = (const float*)d_in[0];
  const float* y  = (const float*)d_in[1];
  const float* U3 = (const float*)d_in[2];
  const float* U2 = (const float*)d_in[3];
  const float* U1 = (const float*)d_in[4];
  const float* W3 = (const float*)d_in[5];
  const float* W2 = (const float*)d_in[6];
  const float* W1 = (const float*)d_in[7];
  float* out = (float*)d_out;

  float* wsU3 = (float*)d_ws;                 // 816*24 floats = 78336 B
  float* wsU2 = wsU3 + NM3 * K3P;             // 136*4 floats  =  2176 B

  prep_kernel<<<dim3(17), dim3(256), 0, stream>>>(U3, U2, wsU3, wsU2);
  // grid: 4 b's per block -> B_/4 = 256 blocks (round-2 crash: this was 512)
  symcon_kernel<<<dim3(B_ / 4), dim3(256), 0, stream>>>(
      x, y, U1, W3, W2, W1, wsU3, wsU2, out);
}